// Round 2
// baseline (1089.748 us; speedup 1.0000x reference)
//
#include <hip/hip_runtime.h>

#define NN 4096
#define TT 12
#define BB 2
#define CC 32
#define WW 10            // T-2 windows
#define K3 12288         // 3*N
#define NCOL 640         // B*W*C
#define SA 4096.0f       // adj scale (2^12)
#define SX 1024.0f       // activation scale (2^10)

typedef _Float16 half8 __attribute__((ext_vector_type(8)));
typedef _Float16 half4_t __attribute__((ext_vector_type(4)));
typedef float floatx4 __attribute__((ext_vector_type(4)));

// ---------------- adj fp32 -> fp16 (scaled) ----------------
__global__ void k_conv_adj(const float* __restrict__ adj, _Float16* __restrict__ a16) {
    long n4 = (long)K3 * K3 / 4;
    long i = (long)blockIdx.x * blockDim.x + threadIdx.x;
    long stride = (long)gridDim.x * blockDim.x;
    const float4* src = (const float4*)adj;
    half4_t* dst = (half4_t*)a16;
    for (; i < n4; i += stride) {
        float4 v = src[i];
        half4_t h;
        h[0] = (_Float16)(v.x * SA);
        h[1] = (_Float16)(v.y * SA);
        h[2] = (_Float16)(v.z * SA);
        h[3] = (_Float16)(v.w * SA);
        dst[i] = h;
    }
}

// ---------------- build X0^T [NCOL][K3] fp16 ----------------
// X0T[bw*32+c][j*N+n] = data[b][w+j][n][c] + temb[w+j][c] + semb[n][c]
__global__ void k_prep(const float* __restrict__ data, const float* __restrict__ temb,
                       const float* __restrict__ semb, _Float16* __restrict__ x0t) {
    __shared__ float sb[CC][64 + 1];
    int z = blockIdx.y;                 // 0..59
    int b = z / 30; int r = z % 30; int w = r / 3; int j = r % 3;
    int t = w + j;
    int n0 = blockIdx.x * 64;
    int tid = threadIdx.x;
    for (int e = tid; e < 64 * CC; e += 256) {
        int nl = e >> 5, c = e & 31;
        float v = data[((long)(b * TT + t) * NN + n0 + nl) * CC + c]
                + temb[t * CC + c] + semb[(n0 + nl) * CC + c];
        sb[c][nl] = v;
    }
    __syncthreads();
    int bw = b * WW + w;
    for (int e = tid; e < 64 * CC; e += 256) {
        int c = e >> 6, nl = e & 63;
        x0t[(long)(bw * CC + c) * K3 + j * NN + n0 + nl] = (_Float16)sb[c][nl];
    }
}

// ---------------- GEMM: G[M][NCOL] = A[M][K] * BT[NCOL][K]^T ----------------
__device__ __forceinline__ void gload_lds16(const _Float16* g, _Float16* l) {
    __builtin_amdgcn_global_load_lds(
        (const __attribute__((address_space(1))) void*)g,
        (__attribute__((address_space(3))) void*)l, 16, 0, 0);
}

__global__ __launch_bounds__(256, 2) void k_gemm(
    const _Float16* __restrict__ A, const _Float16* __restrict__ BT,
    float* __restrict__ G, int K)
{
    __shared__ __attribute__((aligned(16))) _Float16 As[128 * 32];
    __shared__ __attribute__((aligned(16))) _Float16 Bs[128 * 32];

    const int nbn = NCOL / 128;          // 5
    int nwg = gridDim.x;                 // 480 or 160, % 8 == 0
    int cpx = nwg >> 3;
    int bid = blockIdx.x;
    int wg = (bid & 7) * cpx + (bid >> 3);   // XCD-contiguous chunks
    int mt = wg / nbn, nt = wg - mt * nbn;
    long m0 = (long)mt * 128; long n0 = nt * 128;

    int tid = threadIdx.x;
    int lane = tid & 63, wid = tid >> 6;
    int wm = wid >> 1, wn = wid & 1;     // 2x2 waves, 64x64 per wave

    // staging slots: s = i*256 + tid ; row = s>>2, kb = s&3
    // LDS chunk (row,kb) holds global kseg = kb ^ ((row>>1)&3)  (bank swizzle)
    int rowS0 = tid >> 2, kb0 = tid & 3;
    int ks0 = kb0 ^ ((rowS0 >> 1) & 3);
    int s1 = tid + 256;
    int rowS1 = s1 >> 2, kb1 = s1 & 3;
    int ks1 = kb1 ^ ((rowS1 >> 1) & 3);

    const _Float16* aSrc0 = A + (m0 + rowS0) * (long)K + ks0 * 8;
    const _Float16* aSrc1 = A + (m0 + rowS1) * (long)K + ks1 * 8;
    const _Float16* bSrc0 = BT + (n0 + rowS0) * (long)K + ks0 * 8;
    const _Float16* bSrc1 = BT + (n0 + rowS1) * (long)K + ks1 * 8;

    floatx4 acc[4][4] = {};

    int arow = wm * 64 + (lane & 15);
    int brow = wn * 64 + (lane & 15);
    int ksr = lane >> 4;
    int kbA = ksr ^ ((arow >> 1) & 3);   // invariant under row += 16
    int kbB = ksr ^ ((brow >> 1) & 3);

#pragma unroll 1
    for (int k0 = 0; k0 < K; k0 += 32) {
        __syncthreads();
        gload_lds16(aSrc0 + k0, As + wid * 512);
        gload_lds16(aSrc1 + k0, As + 2048 + wid * 512);
        gload_lds16(bSrc0 + k0, Bs + wid * 512);
        gload_lds16(bSrc1 + k0, Bs + 2048 + wid * 512);
        asm volatile("s_waitcnt vmcnt(0)" ::: "memory");
        __syncthreads();

        half8 af[4], bf[4];
#pragma unroll
        for (int ms = 0; ms < 4; ++ms)
            af[ms] = *(const half8*)(As + (arow + ms * 16) * 32 + kbA * 8);
#pragma unroll
        for (int ns = 0; ns < 4; ++ns)
            bf[ns] = *(const half8*)(Bs + (brow + ns * 16) * 32 + kbB * 8);
#pragma unroll
        for (int ms = 0; ms < 4; ++ms)
#pragma unroll
            for (int ns = 0; ns < 4; ++ns)
                acc[ms][ns] = __builtin_amdgcn_mfma_f32_16x16x32_f16(af[ms], bf[ns], acc[ms][ns], 0, 0, 0);
    }

    int rb = (lane >> 4) * 4;
    int cb = lane & 15;
#pragma unroll
    for (int ms = 0; ms < 4; ++ms) {
        long row = m0 + wm * 64 + ms * 16 + rb;
#pragma unroll
        for (int ns = 0; ns < 4; ++ns) {
            long col = n0 + wn * 64 + ns * 16 + cb;
#pragma unroll
            for (int i = 0; i < 4; ++i)
                G[(row + i) * NCOL + col] = acc[ms][ns][i];
        }
    }
}

// ---------------- W-GEMM + GLU ----------------
// MODE 0: write fp16 X^T (scaled by outScale) for next layer
// MODE 1: write fp32 [m][col] (layer 3, cropped rows only)
template <int MODE>
__global__ __launch_bounds__(256) void k_glu(
    const float* __restrict__ G, const float* __restrict__ Wt,
    const float* __restrict__ bias, _Float16* __restrict__ outH,
    float* __restrict__ outF, float invS, float outScale)
{
    __shared__ float Wl[CC * 64];
    __shared__ float bl[64];
    __shared__ _Float16 tb[4][CC][64];
    int tid = threadIdx.x;
    for (int e = tid; e < CC * 64; e += 256) Wl[e] = Wt[e];
    if (tid < 64) bl[tid] = bias[tid];
    __syncthreads();

    int blk = blockIdx.x;
    int mt = blk / 5, bwt = blk % 5;
    int m0 = mt * 64, bw0 = bwt * 4;
    int ml = tid >> 2, bwl = tid & 3;
    int m = m0 + ml, bw = bw0 + bwl;

    const float* gp = G + (long)m * NCOL + bw * CC;
    float g[CC];
#pragma unroll
    for (int c4 = 0; c4 < CC / 4; ++c4) {
        float4 v = ((const float4*)gp)[c4];
        g[c4 * 4 + 0] = v.x * invS; g[c4 * 4 + 1] = v.y * invS;
        g[c4 * 4 + 2] = v.z * invS; g[c4 * 4 + 3] = v.w * invS;
    }
    float y[64];
#pragma unroll
    for (int o = 0; o < 64; ++o) y[o] = bl[o];
#pragma unroll
    for (int c = 0; c < CC; ++c) {
        float gv = g[c];
#pragma unroll
        for (int o = 0; o < 64; ++o) y[o] = fmaf(gv, Wl[c * 64 + o], y[o]);
    }
    if (MODE == 0) {
#pragma unroll
        for (int c = 0; c < CC; ++c) {
            float r = y[c] * (1.f / (1.f + __expf(-y[c + 32])));
            tb[bwl][c][ml] = (_Float16)(r * outScale);
        }
        __syncthreads();
        for (int e = tid; e < 4 * CC * 64; e += 256) {
            int bwl2 = e >> 11, c2 = (e >> 6) & 31, ml2 = e & 63;
            outH[(long)((bw0 + bwl2) * CC + c2) * K3 + m0 + ml2] = tb[bwl2][c2][ml2];
        }
    } else {
        float* op = outF + (long)m * NCOL + bw * CC;
#pragma unroll
        for (int c = 0; c < CC; ++c) {
            float r = y[c] * (1.f / (1.f + __expf(-y[c + 32])));
            op[c] = r;
        }
    }
}

// ---------------- final: max over 3 layers, crop middle, relayout ----------------
__global__ void k_final(const _Float16* __restrict__ x1t, const _Float16* __restrict__ x2t,
                        const float* __restrict__ o3, float* __restrict__ out)
{
    __shared__ float sb[64][CC + 1];
    int bw = blockIdx.y;
    int n0 = blockIdx.x * 64;
    int tid = threadIdx.x;
    for (int e = tid; e < CC * 64; e += 256) {
        int c = e >> 6, nl = e & 63;
        long idx = (long)(bw * CC + c) * K3 + NN + n0 + nl;
        float v1 = (float)x1t[idx] * (1.f / SX);
        float v2 = (float)x2t[idx] * (1.f / SX);
        sb[nl][c] = fmaxf(v1, v2);
    }
    __syncthreads();
    for (int e = tid; e < 64 * CC; e += 256) {
        int nl = e >> 5, c = e & 31;
        float v = fmaxf(sb[nl][c], o3[(long)(n0 + nl) * NCOL + bw * CC + c]);
        out[((long)bw * NN + n0 + nl) * CC + c] = v;
    }
}

extern "C" void kernel_launch(void* const* d_in, const int* in_sizes, int n_in,
                              void* d_out, int out_size, void* d_ws, size_t ws_size,
                              hipStream_t stream)
{
    const float* data = (const float*)d_in[0];
    const float* adj  = (const float*)d_in[1];
    const float* temb = (const float*)d_in[2];
    const float* semb = (const float*)d_in[3];
    const float* W0 = (const float*)d_in[4];
    const float* b0 = (const float*)d_in[5];
    const float* W1 = (const float*)d_in[6];
    const float* b1 = (const float*)d_in[7];
    const float* W2 = (const float*)d_in[8];
    const float* b2 = (const float*)d_in[9];
    float* out = (float*)d_out;

    char* ws = (char*)d_ws;
    _Float16* A16 = (_Float16*)ws;  ws += (size_t)K3 * K3 * 2;        // 302 MB
    _Float16* X0  = (_Float16*)ws;  ws += (size_t)NCOL * K3 * 2;      // 15.7 MB
    _Float16* X1  = (_Float16*)ws;  ws += (size_t)NCOL * K3 * 2;
    _Float16* X2  = (_Float16*)ws;  ws += (size_t)NCOL * K3 * 2;
    float*    G   = (float*)ws;     ws += (size_t)K3 * NCOL * 4;      // 31.5 MB
    float*    O3  = (float*)ws;     ws += (size_t)NN * NCOL * 4;      // 10.5 MB

    k_conv_adj<<<4096, 256, 0, stream>>>(adj, A16);
    k_prep<<<dim3(64, 60), 256, 0, stream>>>(data, temb, semb, X0);

    // layer 1: full 12288 output rows
    k_gemm<<<480, 256, 0, stream>>>(A16, X0, G, K3);
    k_glu<0><<<960, 256, 0, stream>>>(G, W0, b0, X1, nullptr, 1.f / SA, SX);
    // layer 2
    k_gemm<<<480, 256, 0, stream>>>(A16, X1, G, K3);
    k_glu<0><<<960, 256, 0, stream>>>(G, W1, b1, X2, nullptr, 1.f / (SA * SX), SX);
    // layer 3: only middle N rows of A
    k_gemm<<<160, 256, 0, stream>>>(A16 + (size_t)NN * K3, X2, G, K3);
    k_glu<1><<<320, 256, 0, stream>>>(G, W2, b2, nullptr, O3, 1.f / (SA * SX), 1.f);

    k_final<<<dim3(64, 20), 256, 0, stream>>>(X1, X2, O3, out);
}